// Round 1
// baseline (592.312 us; speedup 1.0000x reference)
//
#include <hip/hip_runtime.h>
#include <hip/hip_bf16.h>
#include <math.h>

// ---- problem constants (from reference setup_inputs) ----
#define TT   5
#define CAM  4
#define TC   20      // TT*CAM
#define BB   2
#define CF   32
#define HC   30
#define WC   40
#define MM   1200    // HC*WC
#define NMAX 19      // TC-1 (max pairs per interval)
#define EPSF 1e-12f
#define CHUNK    240  // columns (or rows) staged in LDS per iteration
#define ROWS_PER 240  // rows owned per block (thread-per-row)
#define TILES    5    // MM / ROWS_PER

// ------------------------------------------------------------------
// K1: channel-L2-normalize features and transpose to [pix][CF] rows.
// pred layout: [TC][BB][CF][MM]  ->  dn layout: [TC][BB][MM][CF]
// ------------------------------------------------------------------
__global__ void k_normalize(const float* __restrict__ pred, float* __restrict__ dn) {
  int tb = blockIdx.x; // 0..TC*BB-1
  const float* src = pred + (size_t)tb * CF * MM;
  float*       dst = dn   + (size_t)tb * MM * CF;
  for (int pix = threadIdx.x; pix < MM; pix += blockDim.x) {
    float v[CF];
    float ss = 0.f;
#pragma unroll
    for (int c = 0; c < CF; ++c) { float x = src[c * MM + pix]; v[c] = x; ss = fmaf(x, x, ss); }
    float inv = 1.f / fmaxf(sqrtf(ss), EPSF);
    float4* o = (float4*)(dst + (size_t)pix * CF);
#pragma unroll
    for (int k = 0; k < CF / 4; ++k)
      o[k] = make_float4(v[4*k] * inv, v[4*k+1] * inv, v[4*k+2] * inv, v[4*k+3] * inv);
  }
}

// ------------------------------------------------------------------
// K2: homography (f64) + warped source-cell coordinates per (iv,n,b)
// ------------------------------------------------------------------
__device__ inline void rodrigues_d(const double rv[3], double R[9]) {
  double th = sqrt(rv[0]*rv[0] + rv[1]*rv[1] + rv[2]*rv[2]);
  double thc = fmax(th, 1e-12);
  double kx = rv[0] / thc, ky = rv[1] / thc, kz = rv[2] / thc;
  double st = sin(th), ct = cos(th);
  double Km[9] = { 0.0, -kz,  ky,
                   kz,  0.0, -kx,
                  -ky,  kx,  0.0 };
  double K2[9];
  for (int r = 0; r < 3; ++r)
    for (int c = 0; c < 3; ++c)
      K2[r*3+c] = Km[r*3+0]*Km[0*3+c] + Km[r*3+1]*Km[1*3+c] + Km[r*3+2]*Km[2*3+c];
  for (int r = 0; r < 3; ++r)
    for (int c = 0; c < 3; ++c)
      R[r*3+c] = (r == c ? 1.0 : 0.0) + st * Km[r*3+c] + (1.0 - ct) * K2[r*3+c];
}

__device__ inline void mm3(const double* A, const double* B, double* C) {
  for (int r = 0; r < 3; ++r)
    for (int c = 0; c < 3; ++c)
      C[r*3+c] = A[r*3+0]*B[0*3+c] + A[r*3+1]*B[1*3+c] + A[r*3+2]*B[2*3+c];
}

__global__ void k_warp(const float* __restrict__ rv_, const float* __restrict__ tv_,
                       const float* __restrict__ nts_, const float* __restrict__ dep_,
                       const float* __restrict__ Ks_, const float* __restrict__ Kin_,
                       const float* __restrict__ osz_, const int* __restrict__ ivl,
                       float2* __restrict__ warped) {
  int slot = blockIdx.x;
  int ivi = slot / (NMAX * BB);
  int rem = slot % (NMAX * BB);
  int n = rem / BB, b = rem % BB;
  int iv = ivl[ivi];
  if (n >= TC - iv) return;
  int q0 = n, q1 = n + iv;

  int t0 = q0 / CAM, c0 = q0 % CAM;
  int t1 = q1 / CAM, c1 = q1 % CAM;
  size_t e0 = (size_t)(t0 * BB + b) * CAM + c0; // element index in (T,B,C,...) order
  size_t e1 = (size_t)(t1 * BB + b) * CAM + c1;

  double rv0[3], tv0[3], rv1[3], tv1[3], nv[3];
  for (int k = 0; k < 3; ++k) {
    rv0[k] = rv_[e0*3 + k]; tv0[k] = tv_[e0*3 + k];
    rv1[k] = rv_[e1*3 + k]; tv1[k] = tv_[e1*3 + k];
    nv[k]  = nts_[e0*3 + k];
  }
  double d = dep_[e0];
  double K9[9], Ki9[9];
  for (int k = 0; k < 9; ++k) { K9[k] = Ks_[e0*9 + k]; Ki9[k] = Kin_[e0*9 + k]; }

  double R0[9], R1[9], R[9];
  rodrigues_d(rv0, R0);
  rodrigues_d(rv1, R1);
  // R = R1 @ R0^T
  for (int r = 0; r < 3; ++r)
    for (int c = 0; c < 3; ++c)
      R[r*3+c] = R1[r*3+0]*R0[c*3+0] + R1[r*3+1]*R0[c*3+1] + R1[r*3+2]*R0[c*3+2];
  double tvec[3];
  for (int r = 0; r < 3; ++r)
    tvec[r] = tv1[r] - (R[r*3+0]*tv0[0] + R[r*3+1]*tv0[1] + R[r*3+2]*tv0[2]);
  double Mid[9];
  for (int r = 0; r < 3; ++r)
    for (int c = 0; c < 3; ++c)
      Mid[r*3+c] = R[r*3+c] - tvec[r] * nv[c] / d;
  double T1[9], Hm[9];
  mm3(K9, Mid, T1);
  mm3(T1, Ki9, Hm);

  double osz0 = osz_[e0*2 + 0], osz1 = osz_[e0*2 + 1];
  double s0 = 240.0 / osz0, s1 = 320.0 / osz1;
  double sv[3] = { s1, s0, 1.0 };
  double Hs[9];
  for (int r = 0; r < 3; ++r)
    for (int c = 0; c < 3; ++c)
      Hs[r*3+c] = Hm[r*3+c] * sv[r] / sv[c];

  float2* wout = warped + (size_t)slot * MM;
  for (int cell = threadIdx.x; cell < MM; cell += blockDim.x) {
    double x = (double)((cell % WC) * 8);
    double y = (double)((cell / WC) * 8);
    double wx = Hs[0]*x + Hs[1]*y + Hs[2];
    double wy = Hs[3]*x + Hs[4]*y + Hs[5];
    double wz = Hs[6]*x + Hs[7]*y + Hs[8];
    float z = (float)wz;
    if (fabsf(z) < 1e-8f) z = 1e-8f;
    wout[cell] = make_float2((float)wx / z, (float)wy / z);
  }
}

// ---- common decode helper ----
__device__ inline bool decode_slot(int slot, const int* ivl, int& n, int& b, int& iv) {
  int ivi = slot / (NMAX * BB);
  int rem = slot % (NMAX * BB);
  n = rem / BB; b = rem % BB;
  iv = ivl[ivi];
  return n < TC - iv;
}

// ------------------------------------------------------------------
// K3: row norms. thread-per-row, stream d1 chunks through LDS.
// ------------------------------------------------------------------
__global__ void __launch_bounds__(256) k_rnorm(const float* __restrict__ dn,
                                               const int* __restrict__ ivl,
                                               float* __restrict__ rnorm) {
  __shared__ float sB[CHUNK * CF];
  int slot = blockIdx.x, tile = blockIdx.y;
  int n, b, iv;
  if (!decode_slot(slot, ivl, n, b, iv)) return;
  const float* A  = dn + (size_t)(n * BB + b) * MM * CF;
  const float* Bm = dn + (size_t)((n + iv) * BB + b) * MM * CF;
  int t = threadIdx.x;
  int row = tile * ROWS_PER + (t < ROWS_PER ? t : ROWS_PER - 1);
  float a[CF];
  const float4* arow = (const float4*)(A + (size_t)row * CF);
#pragma unroll
  for (int k = 0; k < 8; ++k) {
    float4 v = arow[k];
    a[4*k] = v.x; a[4*k+1] = v.y; a[4*k+2] = v.z; a[4*k+3] = v.w;
  }
  float acc = 0.f;
  for (int ch = 0; ch < MM / CHUNK; ++ch) {
    const float4* gsrc = (const float4*)(Bm + (size_t)ch * CHUNK * CF);
    for (int idx = t; idx < CHUNK * CF / 4; idx += 256) ((float4*)sB)[idx] = gsrc[idx];
    __syncthreads();
#pragma unroll 1
    for (int j = 0; j < CHUNK; j += 4) {
      const float* b0 = sB + j * CF;
      float s0 = 0.f, s1 = 0.f, s2 = 0.f, s3 = 0.f;
#pragma unroll
      for (int c = 0; c < CF; ++c) {
        float ac = a[c];
        s0 = fmaf(ac, b0[c],        s0);
        s1 = fmaf(ac, b0[c +   CF], s1);
        s2 = fmaf(ac, b0[c + 2*CF], s2);
        s3 = fmaf(ac, b0[c + 3*CF], s3);
      }
      s0 = fmaxf(s0, 0.f); s1 = fmaxf(s1, 0.f); s2 = fmaxf(s2, 0.f); s3 = fmaxf(s3, 0.f);
      acc = fmaf(s0, s0, acc); acc = fmaf(s1, s1, acc);
      acc = fmaf(s2, s2, acc); acc = fmaf(s3, s3, acc);
    }
    __syncthreads();
  }
  if (t < ROWS_PER) rnorm[(size_t)slot * MM + row] = fmaxf(sqrtf(acc), EPSF);
}

// ------------------------------------------------------------------
// K4: column norms of A = S / rnorm. thread-per-column, stream d0 rows.
// ------------------------------------------------------------------
__global__ void __launch_bounds__(256) k_cnorm(const float* __restrict__ dn,
                                               const int* __restrict__ ivl,
                                               const float* __restrict__ rnorm,
                                               float* __restrict__ cnorm) {
  __shared__ float sA[CHUNK * CF];
  __shared__ float sIR[CHUNK];
  int slot = blockIdx.x, tile = blockIdx.y;
  int n, b, iv;
  if (!decode_slot(slot, ivl, n, b, iv)) return;
  const float* A  = dn + (size_t)(n * BB + b) * MM * CF;
  const float* Bm = dn + (size_t)((n + iv) * BB + b) * MM * CF;
  int t = threadIdx.x;
  int col = tile * ROWS_PER + (t < ROWS_PER ? t : ROWS_PER - 1);
  float a[CF];
  const float4* brow = (const float4*)(Bm + (size_t)col * CF);
#pragma unroll
  for (int k = 0; k < 8; ++k) {
    float4 v = brow[k];
    a[4*k] = v.x; a[4*k+1] = v.y; a[4*k+2] = v.z; a[4*k+3] = v.w;
  }
  float acc = 0.f;
  for (int ch = 0; ch < MM / CHUNK; ++ch) {
    const float4* gsrc = (const float4*)(A + (size_t)ch * CHUNK * CF);
    for (int idx = t; idx < CHUNK * CF / 4; idx += 256) ((float4*)sA)[idx] = gsrc[idx];
    for (int idx = t; idx < CHUNK; idx += 256)
      sIR[idx] = 1.f / rnorm[(size_t)slot * MM + ch * CHUNK + idx];
    __syncthreads();
#pragma unroll 1
    for (int i = 0; i < CHUNK; i += 4) {
      const float* b0 = sA + i * CF;
      float s0 = 0.f, s1 = 0.f, s2 = 0.f, s3 = 0.f;
#pragma unroll
      for (int c = 0; c < CF; ++c) {
        float ac = a[c];
        s0 = fmaf(ac, b0[c],        s0);
        s1 = fmaf(ac, b0[c +   CF], s1);
        s2 = fmaf(ac, b0[c + 2*CF], s2);
        s3 = fmaf(ac, b0[c + 3*CF], s3);
      }
      s0 = fmaxf(s0, 0.f) * sIR[i];
      s1 = fmaxf(s1, 0.f) * sIR[i + 1];
      s2 = fmaxf(s2, 0.f) * sIR[i + 2];
      s3 = fmaxf(s3, 0.f) * sIR[i + 3];
      acc = fmaf(s0, s0, acc); acc = fmaf(s1, s1, acc);
      acc = fmaf(s2, s2, acc); acc = fmaf(s3, s3, acc);
    }
    __syncthreads();
  }
  if (t < ROWS_PER) cnorm[(size_t)slot * MM + col] = fmaxf(sqrtf(acc), EPSF);
}

// ------------------------------------------------------------------
// K5: loss. thread-per-row; mask from warped coords; block partials.
// ------------------------------------------------------------------
__global__ void __launch_bounds__(256) k_loss(const float* __restrict__ dn,
                                              const int* __restrict__ ivl,
                                              const float* __restrict__ rnorm,
                                              const float* __restrict__ cnorm,
                                              const float2* __restrict__ warped,
                                              double* __restrict__ partials) {
  __shared__ float sB[CHUNK * CF];
  __shared__ float sIC[CHUNK];
  __shared__ double swsum[4];
  int slot = blockIdx.x, tile = blockIdx.y;
  int pidx = slot * TILES + tile;
  int n, b, iv;
  if (!decode_slot(slot, ivl, n, b, iv)) {
    if (threadIdx.x == 0) partials[pidx] = 0.0;
    return;
  }
  const float* A  = dn + (size_t)(n * BB + b) * MM * CF;
  const float* Bm = dn + (size_t)((n + iv) * BB + b) * MM * CF;
  int t = threadIdx.x;
  int row = tile * ROWS_PER + (t < ROWS_PER ? t : ROWS_PER - 1);
  float a[CF];
  const float4* arow = (const float4*)(A + (size_t)row * CF);
#pragma unroll
  for (int k = 0; k < 8; ++k) {
    float4 v = arow[k];
    a[4*k] = v.x; a[4*k+1] = v.y; a[4*k+2] = v.z; a[4*k+3] = v.w;
  }
  float irn = 1.f / rnorm[(size_t)slot * MM + row];
  float2 wp = warped[(size_t)slot * MM + row];
  float acc = 0.f;
  for (int ch = 0; ch < MM / CHUNK; ++ch) {
    const float4* gsrc = (const float4*)(Bm + (size_t)ch * CHUNK * CF);
    for (int idx = t; idx < CHUNK * CF / 4; idx += 256) ((float4*)sB)[idx] = gsrc[idx];
    for (int idx = t; idx < CHUNK; idx += 256)
      sIC[idx] = 1.f / cnorm[(size_t)slot * MM + ch * CHUNK + idx];
    __syncthreads();
    // CHUNK=240 columns = 6 complete rows of the 30x40 target grid
#pragma unroll 1
    for (int hh = 0; hh < CHUNK / WC; ++hh) {
      float dy = (float)((ch * (CHUNK / WC) + hh) * 8) - wp.y;
      float dy2 = dy * dy;
#pragma unroll 1
      for (int w = 0; w < WC; w += 4) {
        int j = hh * WC + w;
        const float* b0 = sB + j * CF;
        float s0 = 0.f, s1 = 0.f, s2 = 0.f, s3 = 0.f;
#pragma unroll
        for (int c = 0; c < CF; ++c) {
          float ac = a[c];
          s0 = fmaf(ac, b0[c],        s0);
          s1 = fmaf(ac, b0[c +   CF], s1);
          s2 = fmaf(ac, b0[c + 2*CF], s2);
          s3 = fmaf(ac, b0[c + 3*CF], s3);
        }
        float ss[4] = { s0, s1, s2, s3 };
#pragma unroll
        for (int k = 0; k < 4; ++k) {
          float s = fmaxf(ss[k], 0.f);
          float D = s * irn * sIC[j + k];
          float pos = fmaxf(1.0f - D, 0.f);
          float neg = fmaxf(D - 0.2f, 0.f);
          float dx = (float)((w + k) * 8) - wp.x;
          float dd = fmaf(dx, dx, dy2);
          acc += (dd <= 56.25f) ? 0.05f * pos : neg;
        }
      }
    }
    __syncthreads();
  }
  if (t >= ROWS_PER) acc = 0.f;
  // block reduction (4 waves of 64)
  for (int off = 32; off > 0; off >>= 1) acc += __shfl_down(acc, off);
  int wid = t >> 6, lane = t & 63;
  if (lane == 0) swsum[wid] = (double)acc;
  __syncthreads();
  if (t == 0) partials[pidx] = swsum[0] + swsum[1] + swsum[2] + swsum[3];
}

// ------------------------------------------------------------------
// K6: final reduction across partials -> scalar
// ------------------------------------------------------------------
__global__ void k_final(const double* __restrict__ partials, const int* __restrict__ ivl,
                        int niv, float* __restrict__ out) {
  int lane = threadIdx.x; // 64 threads
  double total = 0.0;
  for (int ivi = 0; ivi < niv; ++ivi) {
    double local = 0.0;
    int base = ivi * NMAX * BB * TILES;
    for (int p = lane; p < NMAX * BB * TILES; p += 64) local += partials[base + p];
    for (int off = 32; off > 0; off >>= 1) local += __shfl_down(local, off);
    int N = TC - ivl[ivi];
    total += local / ((double)N * BB * (double)MM * (double)MM);
  }
  if (lane == 0) out[0] = (float)(total / (double)niv);
}

// ------------------------------------------------------------------
extern "C" void kernel_launch(void* const* d_in, const int* in_sizes, int n_in,
                              void* d_out, int out_size, void* d_ws, size_t ws_size,
                              hipStream_t stream) {
  const float* pred = (const float*)d_in[0];
  const float* rv   = (const float*)d_in[1];
  const float* tv   = (const float*)d_in[2];
  const float* nts  = (const float*)d_in[3];
  const float* dep  = (const float*)d_in[4];
  const float* Ks   = (const float*)d_in[5];
  const float* Kin  = (const float*)d_in[6];
  const float* osz  = (const float*)d_in[7];
  const int*   ivl  = (const int*)d_in[8];
  int niv = in_sizes[8];
  int slots = niv * NMAX * BB;

  char* ws = (char*)d_ws;
  size_t off = 0;
  float* dn = (float*)(ws + off);      off += (size_t)TC * BB * MM * CF * 4;
  float2* warped = (float2*)(ws + off); off += (size_t)slots * MM * 2 * 4;
  float* rnorm = (float*)(ws + off);   off += (size_t)slots * MM * 4;
  float* cnorm = (float*)(ws + off);   off += (size_t)slots * MM * 4;
  off = (off + 255) & ~(size_t)255;
  double* partials = (double*)(ws + off); off += (size_t)slots * TILES * 8;

  hipLaunchKernelGGL(k_normalize, dim3(TC * BB), dim3(256), 0, stream, pred, dn);
  hipLaunchKernelGGL(k_warp, dim3(slots), dim3(64), 0, stream,
                     rv, tv, nts, dep, Ks, Kin, osz, ivl, warped);
  hipLaunchKernelGGL(k_rnorm, dim3(slots, TILES), dim3(256), 0, stream, dn, ivl, rnorm);
  hipLaunchKernelGGL(k_cnorm, dim3(slots, TILES), dim3(256), 0, stream, dn, ivl, rnorm, cnorm);
  hipLaunchKernelGGL(k_loss, dim3(slots, TILES), dim3(256), 0, stream,
                     dn, ivl, rnorm, cnorm, warped, partials);
  hipLaunchKernelGGL(k_final, dim3(1), dim3(64), 0, stream, partials, ivl, niv, (float*)d_out);
}

// Round 2
// 167.860 us; speedup vs baseline: 3.5286x; 3.5286x over previous
//
#include <hip/hip_runtime.h>
#include <math.h>

// ---- problem constants ----
#define TT   5
#define CAM  4
#define TC   20
#define BB   2
#define CF   32
#define HC   30
#define WC   40
#define MM   1200
#define NMAX 19
#define EPSF 1e-12f
#define RT   75      // 16-row tiles per item (1200/16)
#define JT   75      // 16-col tiles per item

typedef __attribute__((ext_vector_type(8))) short short8v;   // 8 bf16 (4 VGPR)
typedef __attribute__((ext_vector_type(4))) float float4v;

__device__ inline unsigned short f2bf(float x) {
  unsigned int u = __float_as_uint(x);
  unsigned int r = (u + 0x7FFFu + ((u >> 16) & 1u)) >> 16;  // RNE
  return (unsigned short)r;
}
__device__ inline float bf2f(unsigned short h) {
  return __uint_as_float(((unsigned int)h) << 16);
}

// ------------------------------------------------------------------
// K1: channel-L2-normalize, split into bf16 hi/lo, store MFMA-ready:
// dsp[tcb][sec][pix] (16B each), sec = (hilo ? 4 : 0) + kquarter.
// kquarter q holds channels q*8 .. q*8+7.
// ------------------------------------------------------------------
__global__ void k_split(const float* __restrict__ pred, short8v* __restrict__ dsp) {
  int tb = blockIdx.x;
  const float* src = pred + (size_t)tb * CF * MM;
  short8v*     dst = dsp  + (size_t)tb * 8 * MM;
  for (int pix = threadIdx.x; pix < MM; pix += blockDim.x) {
    float v[CF]; float ss = 0.f;
#pragma unroll
    for (int c = 0; c < CF; ++c) { float x = src[c * MM + pix]; v[c] = x; ss = fmaf(x, x, ss); }
    float inv = 1.f / fmaxf(sqrtf(ss), EPSF);
    unsigned short hi[CF], lo[CF];
#pragma unroll
    for (int c = 0; c < CF; ++c) {
      float xn = v[c] * inv;
      unsigned short h = f2bf(xn);
      hi[c] = h;
      lo[c] = f2bf(xn - bf2f(h));
    }
#pragma unroll
    for (int s = 0; s < 4; ++s) {
      short8v oh, ol;
#pragma unroll
      for (int e = 0; e < 8; ++e) { oh[e] = (short)hi[s*8+e]; ol[e] = (short)lo[s*8+e]; }
      dst[(size_t)s * MM + pix]       = oh;
      dst[(size_t)(4 + s) * MM + pix] = ol;
    }
  }
}

// ------------------------------------------------------------------
// K2: homography (f64) + warped coords per (iv,n,b)  [unchanged]
// ------------------------------------------------------------------
__device__ inline void rodrigues_d(const double rv[3], double R[9]) {
  double th = sqrt(rv[0]*rv[0] + rv[1]*rv[1] + rv[2]*rv[2]);
  double thc = fmax(th, 1e-12);
  double kx = rv[0] / thc, ky = rv[1] / thc, kz = rv[2] / thc;
  double st = sin(th), ct = cos(th);
  double Km[9] = { 0.0, -kz,  ky,  kz, 0.0, -kx,  -ky, kx, 0.0 };
  double K2[9];
  for (int r = 0; r < 3; ++r)
    for (int c = 0; c < 3; ++c)
      K2[r*3+c] = Km[r*3+0]*Km[0*3+c] + Km[r*3+1]*Km[1*3+c] + Km[r*3+2]*Km[2*3+c];
  for (int r = 0; r < 3; ++r)
    for (int c = 0; c < 3; ++c)
      R[r*3+c] = (r == c ? 1.0 : 0.0) + st * Km[r*3+c] + (1.0 - ct) * K2[r*3+c];
}
__device__ inline void mm3(const double* A, const double* B, double* C) {
  for (int r = 0; r < 3; ++r)
    for (int c = 0; c < 3; ++c)
      C[r*3+c] = A[r*3+0]*B[0*3+c] + A[r*3+1]*B[1*3+c] + A[r*3+2]*B[2*3+c];
}

__global__ void k_warp(const float* __restrict__ rv_, const float* __restrict__ tv_,
                       const float* __restrict__ nts_, const float* __restrict__ dep_,
                       const float* __restrict__ Ks_, const float* __restrict__ Kin_,
                       const float* __restrict__ osz_, const int* __restrict__ ivl,
                       float2* __restrict__ warped) {
  int slot = blockIdx.x;
  int ivi = slot / (NMAX * BB);
  int rem = slot % (NMAX * BB);
  int n = rem / BB, b = rem % BB;
  int iv = ivl[ivi];
  if (n >= TC - iv) return;
  int q0 = n, q1 = n + iv;
  int t0 = q0 / CAM, c0 = q0 % CAM;
  int t1 = q1 / CAM, c1 = q1 % CAM;
  size_t e0 = (size_t)(t0 * BB + b) * CAM + c0;
  size_t e1 = (size_t)(t1 * BB + b) * CAM + c1;

  double rv0[3], tv0[3], rv1[3], tv1[3], nv[3];
  for (int k = 0; k < 3; ++k) {
    rv0[k] = rv_[e0*3 + k]; tv0[k] = tv_[e0*3 + k];
    rv1[k] = rv_[e1*3 + k]; tv1[k] = tv_[e1*3 + k];
    nv[k]  = nts_[e0*3 + k];
  }
  double d = dep_[e0];
  double K9[9], Ki9[9];
  for (int k = 0; k < 9; ++k) { K9[k] = Ks_[e0*9 + k]; Ki9[k] = Kin_[e0*9 + k]; }

  double R0[9], R1[9], R[9];
  rodrigues_d(rv0, R0);
  rodrigues_d(rv1, R1);
  for (int r = 0; r < 3; ++r)
    for (int c = 0; c < 3; ++c)
      R[r*3+c] = R1[r*3+0]*R0[c*3+0] + R1[r*3+1]*R0[c*3+1] + R1[r*3+2]*R0[c*3+2];
  double tvec[3];
  for (int r = 0; r < 3; ++r)
    tvec[r] = tv1[r] - (R[r*3+0]*tv0[0] + R[r*3+1]*tv0[1] + R[r*3+2]*tv0[2]);
  double Mid[9];
  for (int r = 0; r < 3; ++r)
    for (int c = 0; c < 3; ++c)
      Mid[r*3+c] = R[r*3+c] - tvec[r] * nv[c] / d;
  double T1[9], Hm[9];
  mm3(K9, Mid, T1);
  mm3(T1, Ki9, Hm);

  double osz0 = osz_[e0*2 + 0], osz1 = osz_[e0*2 + 1];
  double s0 = 240.0 / osz0, s1 = 320.0 / osz1;
  double sv[3] = { s1, s0, 1.0 };
  double Hs[9];
  for (int r = 0; r < 3; ++r)
    for (int c = 0; c < 3; ++c)
      Hs[r*3+c] = Hm[r*3+c] * sv[r] / sv[c];

  float2* wout = warped + (size_t)slot * MM;
  for (int cell = threadIdx.x; cell < MM; cell += blockDim.x) {
    double x = (double)((cell % WC) * 8);
    double y = (double)((cell / WC) * 8);
    double wx = Hs[0]*x + Hs[1]*y + Hs[2];
    double wy = Hs[3]*x + Hs[4]*y + Hs[5];
    double wz = Hs[6]*x + Hs[7]*y + Hs[8];
    float z = (float)wz;
    if (fabsf(z) < 1e-8f) z = 1e-8f;
    wout[cell] = make_float2((float)wx / z, (float)wy / z);
  }
}

__device__ inline bool decode_slot(int slot, const int* ivl, int& n, int& b, int& iv) {
  int ivi = slot / (NMAX * BB);
  int rem = slot % (NMAX * BB);
  n = rem / BB; b = rem % BB;
  iv = ivl[ivi];
  return n < TC - iv;
}

// 2-term bf16-split MFMA: S_tile = Ah*Bh + Ah*Bl + Al*Bh
__device__ inline float4v s_tile(short8v ah, short8v al, short8v bh, short8v bl) {
  float4v acc = {0.f, 0.f, 0.f, 0.f};
  acc = __builtin_amdgcn_mfma_f32_16x16x32_bf16(ah, bh, acc, 0, 0, 0);
  acc = __builtin_amdgcn_mfma_f32_16x16x32_bf16(ah, bl, acc, 0, 0, 0);
  acc = __builtin_amdgcn_mfma_f32_16x16x32_bf16(al, bh, acc, 0, 0, 0);
  return acc;
}

// ------------------------------------------------------------------
// K3: inverse row norms. wave = 16 rows; MFMA over 75 col tiles.
// C/D layout: col = lane&15, row = (lane>>4)*4 + reg.
// ------------------------------------------------------------------
__global__ void __launch_bounds__(256) k_rnorm(const short8v* __restrict__ dsp,
                                               const int* __restrict__ ivl,
                                               float* __restrict__ irn) {
  int slot = blockIdx.x;
  int n, b, iv;
  if (!decode_slot(slot, ivl, n, b, iv)) return;
  int wid = threadIdx.x >> 6, lane = threadIdx.x & 63;
  int rowtile = blockIdx.y * 4 + wid;
  if (rowtile >= RT) return;
  int q = lane >> 4, li = lane & 15;
  const short8v* D0 = dsp + (size_t)(n * BB + b) * 8 * MM;
  const short8v* D1 = dsp + (size_t)((n + iv) * BB + b) * 8 * MM;
  int row16 = rowtile * 16;
  short8v ah = D0[(size_t)q * MM + row16 + li];
  short8v al = D0[(size_t)(q + 4) * MM + row16 + li];
  float4v racc = {0.f, 0.f, 0.f, 0.f};
#pragma unroll 3
  for (int jt = 0; jt < JT; ++jt) {
    int jp = jt * 16 + li;
    short8v bh = D1[(size_t)q * MM + jp];
    short8v bl = D1[(size_t)(q + 4) * MM + jp];
    float4v acc = s_tile(ah, al, bh, bl);
#pragma unroll
    for (int r = 0; r < 4; ++r) { float t = fmaxf(acc[r], 0.f); racc[r] = fmaf(t, t, racc[r]); }
  }
#pragma unroll
  for (int m = 1; m <= 8; m <<= 1)
#pragma unroll
    for (int r = 0; r < 4; ++r) racc[r] += __shfl_xor(racc[r], m);
  if (li == 0) {
#pragma unroll
    for (int r = 0; r < 4; ++r)
      irn[(size_t)slot * MM + row16 + q * 4 + r] = 1.f / fmaxf(sqrtf(racc[r]), EPSF);
  }
}

// ------------------------------------------------------------------
// K4: inverse col norms of (relu(S)/rnorm_i). wave = 16 cols (j);
// computes T[j][i] = d1_j . d0_i, scales by irn[i], accumulates sq.
// ------------------------------------------------------------------
__global__ void __launch_bounds__(256) k_cnorm(const short8v* __restrict__ dsp,
                                               const int* __restrict__ ivl,
                                               const float* __restrict__ irn,
                                               float* __restrict__ icn) {
  int slot = blockIdx.x;
  int n, b, iv;
  if (!decode_slot(slot, ivl, n, b, iv)) return;
  int wid = threadIdx.x >> 6, lane = threadIdx.x & 63;
  int coltile = blockIdx.y * 4 + wid;
  if (coltile >= RT) return;
  int q = lane >> 4, li = lane & 15;
  const short8v* D0 = dsp + (size_t)(n * BB + b) * 8 * MM;
  const short8v* D1 = dsp + (size_t)((n + iv) * BB + b) * 8 * MM;
  int col16 = coltile * 16;
  short8v ah = D1[(size_t)q * MM + col16 + li];
  short8v al = D1[(size_t)(q + 4) * MM + col16 + li];
  const float* irnS = irn + (size_t)slot * MM;
  float4v cacc = {0.f, 0.f, 0.f, 0.f};
#pragma unroll 3
  for (int it = 0; it < JT; ++it) {
    int ip = it * 16 + li;
    short8v bh = D0[(size_t)q * MM + ip];
    short8v bl = D0[(size_t)(q + 4) * MM + ip];
    float4v acc = s_tile(ah, al, bh, bl);
    float ir = irnS[ip];   // i = ip = C-col index for this lane
#pragma unroll
    for (int r = 0; r < 4; ++r) { float t = fmaxf(acc[r], 0.f) * ir; cacc[r] = fmaf(t, t, cacc[r]); }
  }
#pragma unroll
  for (int m = 1; m <= 8; m <<= 1)
#pragma unroll
    for (int r = 0; r < 4; ++r) cacc[r] += __shfl_xor(cacc[r], m);
  if (li == 0) {
#pragma unroll
    for (int r = 0; r < 4; ++r)
      icn[(size_t)slot * MM + col16 + q * 4 + r] = 1.f / fmaxf(sqrtf(cacc[r]), EPSF);
  }
}

// ------------------------------------------------------------------
// K5: loss. wave = 16 rows (i); loops 75 j tiles; hinge + mask epilogue.
// ------------------------------------------------------------------
__global__ void __launch_bounds__(256) k_loss(const short8v* __restrict__ dsp,
                                              const int* __restrict__ ivl,
                                              const float* __restrict__ irn,
                                              const float* __restrict__ icn,
                                              const float2* __restrict__ warped,
                                              double* __restrict__ partials) {
  int slot = blockIdx.x;
  int wid = threadIdx.x >> 6, lane = threadIdx.x & 63;
  int rowtile = blockIdx.y * 4 + wid;
  int n, b, iv;
  bool valid = decode_slot(slot, ivl, n, b, iv);
  if (!valid) {
    if (rowtile < RT && lane == 0) partials[(size_t)slot * RT + rowtile] = 0.0;
    return;
  }
  if (rowtile >= RT) return;
  int q = lane >> 4, li = lane & 15;
  const short8v* D0 = dsp + (size_t)(n * BB + b) * 8 * MM;
  const short8v* D1 = dsp + (size_t)((n + iv) * BB + b) * 8 * MM;
  int row16 = rowtile * 16;
  short8v ah = D0[(size_t)q * MM + row16 + li];
  short8v al = D0[(size_t)(q + 4) * MM + row16 + li];
  float irn4[4], wx4[4], wy4[4];
#pragma unroll
  for (int r = 0; r < 4; ++r) {
    int row = row16 + q * 4 + r;
    irn4[r] = irn[(size_t)slot * MM + row];
    float2 wp = warped[(size_t)slot * MM + row];
    wx4[r] = wp.x; wy4[r] = wp.y;
  }
  const float* icnS = icn + (size_t)slot * MM;
  float lacc = 0.f;
#pragma unroll 3
  for (int jt = 0; jt < JT; ++jt) {
    int jp = jt * 16 + li;
    short8v bh = D1[(size_t)q * MM + jp];
    short8v bl = D1[(size_t)(q + 4) * MM + jp];
    float4v acc = s_tile(ah, al, bh, bl);
    float ic = icnS[jp];
    float cx = (float)((jp % WC) * 8);
    float cy = (float)((jp / WC) * 8);
#pragma unroll
    for (int r = 0; r < 4; ++r) {
      float s = fmaxf(acc[r], 0.f) * ic;
      float Dv = s * irn4[r];
      float pos = fmaxf(1.0f - Dv, 0.f);
      float neg = fmaxf(Dv - 0.2f, 0.f);
      float dx = cx - wx4[r], dy = cy - wy4[r];
      float dd = fmaf(dx, dx, dy * dy);
      lacc += (dd <= 56.25f) ? 0.05f * pos : neg;
    }
  }
#pragma unroll
  for (int off = 32; off > 0; off >>= 1) lacc += __shfl_xor(lacc, off);
  if (lane == 0) partials[(size_t)slot * RT + rowtile] = (double)lacc;
}

// ------------------------------------------------------------------
// K6: final reduction
// ------------------------------------------------------------------
__global__ void k_final(const double* __restrict__ partials, const int* __restrict__ ivl,
                        int niv, float* __restrict__ out) {
  int lane = threadIdx.x; // 64 threads
  double total = 0.0;
  for (int ivi = 0; ivi < niv; ++ivi) {
    double local = 0.0;
    int base = ivi * NMAX * BB * RT;
    for (int p = lane; p < NMAX * BB * RT; p += 64) local += partials[base + p];
    for (int off = 32; off > 0; off >>= 1) local += __shfl_down(local, off);
    int N = TC - ivl[ivi];
    total += local / ((double)N * BB * (double)MM * (double)MM);
  }
  if (lane == 0) out[0] = (float)(total / (double)niv);
}

// ------------------------------------------------------------------
extern "C" void kernel_launch(void* const* d_in, const int* in_sizes, int n_in,
                              void* d_out, int out_size, void* d_ws, size_t ws_size,
                              hipStream_t stream) {
  const float* pred = (const float*)d_in[0];
  const float* rv   = (const float*)d_in[1];
  const float* tv   = (const float*)d_in[2];
  const float* nts  = (const float*)d_in[3];
  const float* dep  = (const float*)d_in[4];
  const float* Ks   = (const float*)d_in[5];
  const float* Kin  = (const float*)d_in[6];
  const float* osz  = (const float*)d_in[7];
  const int*   ivl  = (const int*)d_in[8];
  int niv = in_sizes[8];
  int slots = niv * NMAX * BB;

  char* ws = (char*)d_ws;
  size_t off = 0;
  short8v* dsp = (short8v*)(ws + off); off += (size_t)TC * BB * 8 * MM * 16;
  float2* warped = (float2*)(ws + off); off += (size_t)slots * MM * 8;
  float* irn = (float*)(ws + off);     off += (size_t)slots * MM * 4;
  float* icn = (float*)(ws + off);     off += (size_t)slots * MM * 4;
  off = (off + 255) & ~(size_t)255;
  double* partials = (double*)(ws + off); off += (size_t)slots * RT * 8;

  hipLaunchKernelGGL(k_split, dim3(TC * BB), dim3(256), 0, stream, pred, dsp);
  hipLaunchKernelGGL(k_warp, dim3(slots), dim3(64), 0, stream,
                     rv, tv, nts, dep, Ks, Kin, osz, ivl, warped);
  dim3 grid(slots, (RT + 3) / 4);
  hipLaunchKernelGGL(k_rnorm, grid, dim3(256), 0, stream, dsp, ivl, irn);
  hipLaunchKernelGGL(k_cnorm, grid, dim3(256), 0, stream, dsp, ivl, irn, icn);
  hipLaunchKernelGGL(k_loss, grid, dim3(256), 0, stream,
                     dsp, ivl, irn, icn, warped, partials);
  hipLaunchKernelGGL(k_final, dim3(1), dim3(64), 0, stream, partials, ivl, niv, (float*)d_out);
}